// Round 4
// baseline (273.945 us; speedup 1.0000x reference)
//
#include <hip/hip_runtime.h>
#include <hip/hip_bf16.h>

#define BATCH 2
#define SEQ   2048
#define DIM   2048
#define NHEAD 16
#define HDIM  128

// LDS strides (elements) for attn V/P tiles. Multiples of 8 (16B alignment).
#define VSTRIDE 72
#define PSTRIDE 72

typedef __bf16 bf16;
typedef __attribute__((ext_vector_type(2))) __bf16 bf16x2;
typedef __attribute__((ext_vector_type(4))) __bf16 bf16x4;
typedef __attribute__((ext_vector_type(8))) __bf16 bf16x8;
typedef __attribute__((ext_vector_type(4))) float f32x4;

__device__ __forceinline__ void load_lds16(const bf16* g, bf16* l) {
    __builtin_amdgcn_global_load_lds((const __attribute__((address_space(1))) void*)g,
                                     (__attribute__((address_space(3))) void*)l, 16, 0, 0);
}

// v_exp_f32: D = 2^S0 (hardware transcendental)
__device__ __forceinline__ float exp2_hw(float x) { return __builtin_amdgcn_exp2f(x); }

// ---------------------------------------------------------------------------
// Fused prep (single dispatch, tasks run concurrently):
//   blocks [0, 4096):        cvt x fp32 -> xb bf16 (8 elems/thread)
//   blocks [4096, 5120):     transpose Wq -> Wtq (64x64 tiles)
//   blocks [5120, 6144):     transpose Wo -> Wto
// ---------------------------------------------------------------------------
__global__ __launch_bounds__(256)
void prep_kernel(const float* __restrict__ x, bf16* __restrict__ xb,
                 const float* __restrict__ Wq, bf16* __restrict__ Wtq,
                 const float* __restrict__ Wo, bf16* __restrict__ Wto)
{
    __shared__ bf16 T[64 * 72];
    const int bid = blockIdx.x;
    if (bid < 4096) {
        const size_t i = ((size_t)bid * 256 + threadIdx.x) * 8;
        const float4 f0 = *(const float4*)(x + i);
        const float4 f1 = *(const float4*)(x + i + 4);
        *(bf16x8*)(xb + i) = (bf16x8){(bf16)f0.x, (bf16)f0.y, (bf16)f0.z, (bf16)f0.w,
                                      (bf16)f1.x, (bf16)f1.y, (bf16)f1.z, (bf16)f1.w};
        return;
    }
    int t = bid - 4096;
    const float* W  = (t < 1024) ? Wq : Wo;
    bf16*        Wt = (t < 1024) ? Wtq : Wto;
    t &= 1023;
    const int kb = (t >> 5) * 64, nb = (t & 31) * 64;

    const int a = threadIdx.x & 31;     // k-pair index
    const int g = threadIdx.x >> 5;     // n-slice 0..7
    {
        const float* s0 = W + (size_t)(kb + 2 * a) * DIM + nb + g * 8;
        const float4 r0a = *(const float4*)(s0);
        const float4 r0b = *(const float4*)(s0 + 4);
        const float4 r1a = *(const float4*)(s0 + DIM);
        const float4 r1b = *(const float4*)(s0 + DIM + 4);
        float v0[8] = {r0a.x, r0a.y, r0a.z, r0a.w, r0b.x, r0b.y, r0b.z, r0b.w};
        float v1[8] = {r1a.x, r1a.y, r1a.z, r1a.w, r1b.x, r1b.y, r1b.z, r1b.w};
        #pragma unroll
        for (int i = 0; i < 8; ++i)
            *(bf16x2*)&T[(g * 8 + i) * 72 + 2 * a] = (bf16x2){(bf16)v0[i], (bf16)v1[i]};
    }
    __syncthreads();

    const int r  = threadIdx.x >> 2;          // output n row 0..63
    const int k0 = (threadIdx.x & 3) * 16;    // k chunk
    bf16x8 o0 = *(const bf16x8*)&T[r * 72 + k0];
    bf16x8 o1 = *(const bf16x8*)&T[r * 72 + k0 + 8];
    *(bf16x8*)(Wt + (size_t)(nb + r) * DIM + kb + k0)     = o0;
    *(bf16x8*)(Wt + (size_t)(nb + r) * DIM + kb + k0 + 8) = o1;
}

// ---------------------------------------------------------------------------
// GEMM, 8-phase counted-vmcnt (unchanged from round 3 — passed refcheck):
//   C[M,N] = A[M,K] @ Bt[N,K]^T, bf16 in. BM=128, BN=256, 8 waves 2Mx4N,
//   K in 64 slices of 32, 4-slot LDS ring (96 KiB), 256 blocks = 256 CUs.
// ---------------------------------------------------------------------------
#define GEMM_PHASE(S, VM, DO_STAGE)                                            \
    {                                                                          \
        const bf16* Aq = Ls + ((S) & 3) * 12288;                               \
        const bf16* Bq = Aq + 4096;                                            \
        bf16x8 a[4], b[4];                                                     \
        _Pragma("unroll")                                                      \
        for (int i = 0; i < 4; ++i) a[i] = *(const bf16x8*)(Aq + offA[i]);     \
        _Pragma("unroll")                                                      \
        for (int j = 0; j < 4; ++j) b[j] = *(const bf16x8*)(Bq + offB[j]);     \
        if (DO_STAGE) {                                                        \
            bf16* lb = Ls + (((S) + 3) & 3) * 12288 + wave * 512;              \
            const int ko = ((S) + 3) * 32;                                     \
            load_lds16(gA + ko, lb);                                           \
            load_lds16(gB0 + ko, lb + 4096);                                   \
            load_lds16(gB1 + ko, lb + 8192);                                   \
        }                                                                      \
        __builtin_amdgcn_s_barrier();                                          \
        __builtin_amdgcn_s_setprio(1);                                         \
        _Pragma("unroll")                                                      \
        for (int i = 0; i < 4; ++i) {                                          \
            _Pragma("unroll")                                                  \
            for (int j = 0; j < 4; ++j)                                        \
                acc[i][j] = __builtin_amdgcn_mfma_f32_16x16x32_bf16(a[i], b[j], acc[i][j], 0, 0, 0); \
        }                                                                      \
        __builtin_amdgcn_s_setprio(0);                                         \
        if ((VM) == 6)      asm volatile("s_waitcnt vmcnt(6)" ::: "memory");   \
        else if ((VM) == 3) asm volatile("s_waitcnt vmcnt(3)" ::: "memory");   \
        else if ((VM) == 0) asm volatile("s_waitcnt vmcnt(0)" ::: "memory");   \
        if ((VM) >= 0) {                                                       \
            __builtin_amdgcn_s_barrier();                                      \
            asm volatile("" ::: "memory");                                     \
        }                                                                      \
    }

template<bool OUT_F32_BIAS>
__global__ __launch_bounds__(512, 2)
void gemm_bt8(const bf16* __restrict__ A, const bf16* __restrict__ Bt,
              const float* __restrict__ bias, void* __restrict__ Cptr,
              int M, int N, int K)
{
    __shared__ bf16 Ls[4 * 12288];   // 96 KiB ring: slot = A[128][32] + B[256][32]

    const int tid  = threadIdx.x;
    const int wave = tid >> 6;        // 0..7
    const int lane = tid & 63;
    const int quad = lane >> 4;
    const int l16  = lane & 15;
    const int wr   = wave >> 2;       // 0..1: 64-row block
    const int wc   = wave & 3;        // 0..3: 64-col block

    // XCD swizzle (bijective: 256 blocks, 256%8==0).
    const int cpx = gridDim.x >> 3;
    const int logical = (blockIdx.x & 7) * cpx + (blockIdx.x >> 3);
    const int rowBase = (logical >> 3) * 128;   // NT = N/256 = 8
    const int colBase = (logical & 7) * 256;

    // s-invariant swizzled ds_read element offsets (region-relative)
    int offA[4], offB[4];
    #pragma unroll
    for (int i = 0; i < 4; ++i) {
        int e = (wr * 64 + i * 16 + l16) * 32 + quad * 8;
        offA[i] = e ^ (((e >> 6) & 3) << 3);
    }
    #pragma unroll
    for (int j = 0; j < 4; ++j) {
        int e = (wc * 64 + j * 16 + l16) * 32 + quad * 8;
        offB[j] = e ^ (((e >> 6) & 3) << 3);
    }

    // Staging source decode: lane's linear LDS slot offset o holds logical
    // elem swz(o) (involution) -> per-lane global addr pre-swizzled.
    const int oA  = wave * 512 + lane * 8;
    const int eA  = oA ^ (((oA >> 6) & 3) << 3);
    const bf16* gA  = A  + (size_t)(rowBase + (eA >> 5)) * K + (eA & 31);
    const int oB0 = wave * 512 + lane * 8;
    const int eB0 = oB0 ^ (((oB0 >> 6) & 3) << 3);
    const bf16* gB0 = Bt + (size_t)(colBase + (eB0 >> 5)) * K + (eB0 & 31);
    const int oB1 = 4096 + wave * 512 + lane * 8;
    const int eB1 = oB1 ^ (((oB1 >> 6) & 3) << 3);
    const bf16* gB1 = Bt + (size_t)(colBase + ((eB1 - 4096) >> 5) + 128) * K + (eB1 & 31);

    f32x4 acc[4][4] = {};

    // prologue: slices 0,1,2 in flight (9 loads/wave), wait oldest -> vmcnt(6)
    #pragma unroll
    for (int s = 0; s < 3; ++s) {
        bf16* lb = Ls + s * 12288 + wave * 512;
        load_lds16(gA  + s * 32, lb);
        load_lds16(gB0 + s * 32, lb + 4096);
        load_lds16(gB1 + s * 32, lb + 8192);
    }
    asm volatile("s_waitcnt vmcnt(6)" ::: "memory");
    __builtin_amdgcn_s_barrier();
    asm volatile("" ::: "memory");

    for (int s = 0; s < 61; ++s)
        GEMM_PHASE(s, 6, true);
    GEMM_PHASE(61, 3, false);
    GEMM_PHASE(62, 0, false);
    GEMM_PHASE(63, -1, false);

    // epilogue: C row = quad*4+r, col = l16 within each 16x16 fragment
    #pragma unroll
    for (int i = 0; i < 4; ++i) {
        #pragma unroll
        for (int j = 0; j < 4; ++j) {
            #pragma unroll
            for (int r = 0; r < 4; ++r) {
                const int row = rowBase + wr * 64 + i * 16 + quad * 4 + r;
                const int col = colBase + wc * 64 + j * 16 + l16;
                const float v = acc[i][j][r];
                if (OUT_F32_BIAS) ((float*)Cptr)[(size_t)row * N + col] = v + bias[col];
                else              ((bf16*)Cptr)[(size_t)row * N + col] = (bf16)v;
            }
        }
    }
}

// ---------------------------------------------------------------------------
// Attention, round-4 K-path rework:
//   * K staged via global_load_lds DMA into a double-buffered LINEAR
//     Ks[2][64][128] (no reg round-trip, no LDS-write ops).
//   * XOR swizzle (T2, rule #21 both-sides): tile byte d holds logical byte
//     l = d ^ ((row&7)<<4), row = d>>8. DMA dest linear; global SOURCE is
//     pre-swizzled; ds_read applies the same involution. Bank audit: rows
//     0..7 -> 8 distinct 16B slots -> 32 banks, residual 2-way = free.
//   * vmcnt ledger: issue order per iter = [K(kt+1) DMA x4][V(kt+1) b128 x4].
//     In-order vmcnt retirement (m135) means the V(kt)-commit's implicit
//     positional wait also retires the older K(kt) DMAs => K(kt) is in LDS
//     before barrier2 with NO explicit drain; K(kt+1)/V(kt+1) stay in
//     flight across the whole compute phase.
//   * All 16 ak fragment reads hoisted (akr[4][4], +64 VGPR) — one lgkm
//     burst instead of 4 serial stall points.
// V path (reg prefetch + transposed commit) and S^T/PV/epilogue unchanged.
// ---------------------------------------------------------------------------
__global__ __launch_bounds__(256, 2)
void attn_kernel(const bf16* __restrict__ q, bf16* __restrict__ y)
{
    __shared__ bf16 Ks[2 * 64 * 128];     // 32768 B, dbuf, swizzled-linear
    __shared__ bf16 Vt[HDIM * VSTRIDE];   // 18432 B  [hd][kv]
    __shared__ bf16 Ps[128 * PSTRIDE];    // 18432 B  [q][kv]

    const int tid  = threadIdx.x;
    const int wave = tid >> 6;     // 0..3
    const int lane = tid & 63;
    const int quad = lane >> 4;
    const int l16  = lane & 15;

    // XCD swizzle: p -> (qt, h, b) with all qt of a (b,h) on one XCD.
    const int p   = blockIdx.x;
    const int xcd = p & 7;
    const int pos = p >> 3;
    const int g   = xcd * 4 + (pos & 3);   // (b,h) group 0..31
    const int qt  = pos >> 2;              // 0..15
    const int h   = g & 15;
    const int bb  = g >> 4;

    const bf16* qb = q + (size_t)bb * SEQ * DIM + (size_t)h * HDIM;

    // Q fragments -> registers (wave owns q rows [wave*32, wave*32+32)).
    const float qs = 0.12752820031096662f;   // (1/sqrt(128)) * log2(e)
    bf16x8 aq[2][4];
    #pragma unroll
    for (int nt = 0; nt < 2; ++nt) {
        #pragma unroll
        for (int ks = 0; ks < 4; ++ks) {
            const bf16* src = qb + (size_t)(qt * 128 + wave * 32 + nt * 16 + l16) * DIM + ks * 32 + quad * 8;
            bf16x8 v = *(const bf16x8*)src;
            bf16x8 o;
            #pragma unroll
            for (int e = 0; e < 8; ++e) o[e] = (bf16)((float)v[e] * qs);
            aq[nt][ks] = o;
        }
    }

    float lpart[2] = {0.f, 0.f};
    f32x4 yacc[2][8] = {};

    // K DMA source: dest slot d = tid*16 + c*4096 bytes; row = (tid>>4)+c*16;
    // logical col byte = ((tid&15)<<4) ^ (((tid>>4)&7)<<4)  (c-independent
    // since c*16 == 0 mod 8). 16-lane groups read a permuted but contiguous
    // 256B row => coalesced.
    const int colK = ((((tid & 15) << 4) ^ (((tid >> 4) & 7) << 4)) >> 1);
    const bf16* srcK = qb + (size_t)(tid >> 4) * DIM + colK;

    // V staging map (conflict-free transposed commit, unchanged)
    const int sp   = tid & 31;         // kv pair
    const int ss   = tid >> 5;         // hd slice of 16
    const bf16* srcV = qb + (size_t)(2 * sp) * DIM + ss * 16;

    // prologue: K(0) DMA + V(0) reg prefetch
    #pragma unroll
    for (int c = 0; c < 4; ++c)
        load_lds16(srcK + (size_t)c * 16 * DIM, Ks + tid * 8 + c * 2048);
    bf16x8 va[2], vb[2];
    va[0] = *(const bf16x8*)(srcV + 0);
    va[1] = *(const bf16x8*)(srcV + 8);
    vb[0] = *(const bf16x8*)(srcV + DIM + 0);
    vb[1] = *(const bf16x8*)(srcV + DIM + 8);

    for (int kt = 0; kt < SEQ / 64; ++kt) {
        __syncthreads();   // barrier1: prev tile's readers done

        // issue K(kt+1) DMA into the other Ks slot (overlaps compute of kt)
        if (kt + 1 < SEQ / 64) {
            bf16* kd = Ks + ((kt + 1) & 1) * 8192 + tid * 8;
            const bf16* kg = srcK + (size_t)(kt + 1) * 64 * DIM;
            #pragma unroll
            for (int c = 0; c < 4; ++c)
                load_lds16(kg + (size_t)c * 16 * DIM, kd + c * 2048);
        }

        // commit V(kt): implicit positional vmcnt here also retires K(kt)
        #pragma unroll
        for (int c = 0; c < 2; ++c)
            #pragma unroll
            for (int e = 0; e < 8; ++e)
                *(bf16x2*)&Vt[(ss * 16 + c * 8 + e) * VSTRIDE + 2 * sp] = (bf16x2){va[c][e], vb[c][e]};

        // prefetch V(kt+1) regs (in flight across compute)
        if (kt + 1 < SEQ / 64) {
            const bf16* nV = srcV + (size_t)(kt + 1) * 64 * DIM;
            va[0] = *(const bf16x8*)(nV + 0);
            va[1] = *(const bf16x8*)(nV + 8);
            vb[0] = *(const bf16x8*)(nV + DIM + 0);
            vb[1] = *(const bf16x8*)(nV + DIM + 8);
        }
        __syncthreads();   // barrier2: K(kt) landed, V(kt) committed
        asm volatile("" ::: "memory");

        // bulk ak fragment load (hoisted, swizzled read)
        const bf16* Kb = Ks + (kt & 1) * 8192;
        bf16x8 akr[4][4];
        #pragma unroll
        for (int mt = 0; mt < 4; ++mt) {
            #pragma unroll
            for (int ks = 0; ks < 4; ++ks) {
                const int cb = (ks * 64 + quad * 16) ^ ((l16 & 7) << 4);
                akr[mt][ks] = *(const bf16x8*)(Kb + (mt * 16 + l16) * 128 + (cb >> 1));
            }
        }

        // S^T phase per 16-kv strip (mt): MFMA(A=K-frag, B=aq).
        // C-layout of S^T: kv = mt*16 + quad*4 + r, q = wave*32 + nt*16 + l16.
        #pragma unroll
        for (int mt = 0; mt < 4; ++mt) {
            f32x4 s[2] = {};
            __builtin_amdgcn_s_setprio(1);
            #pragma unroll
            for (int ks = 0; ks < 4; ++ks)
                #pragma unroll
                for (int nt = 0; nt < 2; ++nt)
                    s[nt] = __builtin_amdgcn_mfma_f32_16x16x32_bf16(akr[mt][ks], aq[nt][ks], s[nt], 0, 0, 0);
            __builtin_amdgcn_s_setprio(0);
            #pragma unroll
            for (int nt = 0; nt < 2; ++nt) {
                float p0 = exp2_hw(s[nt][0]);
                float p1 = exp2_hw(s[nt][1]);
                float p2 = exp2_hw(s[nt][2]);
                float p3 = exp2_hw(s[nt][3]);
                lpart[nt] += (p0 + p1) + (p2 + p3);
                *(bf16x4*)&Ps[(wave * 32 + nt * 16 + l16) * PSTRIDE + mt * 16 + quad * 4] =
                    (bf16x4){(bf16)p0, (bf16)p1, (bf16)p2, (bf16)p3};
            }
        }

        // PV: Y += P @ V. A = own-wave P rows (in-wave LDS dep only), B = V^T.
        #pragma unroll
        for (int ks2 = 0; ks2 < 2; ++ks2) {
            bf16x8 ap[2];
            #pragma unroll
            for (int i = 0; i < 2; ++i)
                ap[i] = *(const bf16x8*)&Ps[(wave * 32 + i * 16 + l16) * PSTRIDE + ks2 * 32 + quad * 8];
            __builtin_amdgcn_s_setprio(1);
            #pragma unroll
            for (int n = 0; n < 8; ++n) {
                bf16x8 bv = *(const bf16x8*)&Vt[(n * 16 + l16) * VSTRIDE + ks2 * 32 + quad * 8];
                #pragma unroll
                for (int i = 0; i < 2; ++i)
                    yacc[i][n] = __builtin_amdgcn_mfma_f32_16x16x32_bf16(ap[i], bv, yacc[i][n], 0, 0, 0);
            }
            __builtin_amdgcn_s_setprio(0);
        }
    }

    // denominators: reduce across the 4 quad-lanes sharing each q.
    float lfull[2];
    #pragma unroll
    for (int nt = 0; nt < 2; ++nt) {
        float l = lpart[nt];
        l += __shfl_xor(l, 16);
        l += __shfl_xor(l, 32);
        lfull[nt] = l;
    }

    // epilogue: yacc C-layout row = wave*32 + i*16 + quad*4 + r (q),
    // col = n*16 + l16 (hd).
    bf16* yb = y + (size_t)bb * SEQ * DIM + (size_t)(qt * 128) * DIM + (size_t)h * HDIM;
    #pragma unroll
    for (int i = 0; i < 2; ++i) {
        #pragma unroll
        for (int r = 0; r < 4; ++r) {
            const float lv  = __shfl(lfull[i], (lane & 48) | (quad * 4 + r));
            const float inv = 1.f / lv;
            const int row = wave * 32 + i * 16 + quad * 4 + r;
            #pragma unroll
            for (int n = 0; n < 8; ++n)
                yb[(size_t)row * DIM + n * 16 + l16] = (bf16)(yacc[i][n][r] * inv);
        }
    }
}

// ---------------------------------------------------------------------------
// Workspace layout (unchanged):
//   ws[0 .. N)        qws  (gemm1 out, attn in)           N = 16.78 MB
//   ws[N .. 2N)       yws  (attn out, gemm2 in); first 8.39 MB doubles as Wtq
//   ws[2N .. 2N+W)    Wto                                  W = 8.39 MB
//   d_out[0 .. N)     xb   (bf16 scratch; dead before gemm2 overwrites d_out)
// ---------------------------------------------------------------------------
extern "C" void kernel_launch(void* const* d_in, const int* in_sizes, int n_in,
                              void* d_out, int out_size, void* d_ws, size_t ws_size,
                              hipStream_t stream)
{
    const float* x  = (const float*)d_in[0];
    const float* Wq = (const float*)d_in[1];
    const float* Wo = (const float*)d_in[2];
    const float* bo = (const float*)d_in[3];
    float* out = (float*)d_out;

    const size_t NELEM = (size_t)BATCH * SEQ * DIM;
    bf16* qws = (bf16*)d_ws;
    bf16* yws = qws + NELEM;
    bf16* Wtq = yws;                 // aliased: safe, gemm1 precedes attn
    bf16* Wto = qws + 2 * NELEM;
    bf16* xb  = (bf16*)d_out;        // scratch inside d_out, dead by gemm2

    const int M = BATCH * SEQ;       // 4096

    prep_kernel<<<6144, 256, 0, stream>>>(x, xb, Wq, Wtq, Wo, Wto);
    gemm_bt8<false><<<256, 512, 0, stream>>>(xb, Wtq, nullptr, qws, M, DIM, DIM);
    attn_kernel<<<512, 256, 0, stream>>>(qws, yws);
    gemm_bt8<true><<<256, 512, 0, stream>>>(yws, Wto, bo, out, M, DIM, DIM);
}

// Round 5
// 265.966 us; speedup vs baseline: 1.0300x; 1.0300x over previous
//
#include <hip/hip_runtime.h>
#include <hip/hip_bf16.h>

#define BATCH 2
#define SEQ   2048
#define DIM   2048
#define NHEAD 16
#define HDIM  128

// LDS strides (elements) for attn. Multiples of 8 (16B alignment for b128).
#define KSTRIDE 136
#define VSTRIDE 72
#define PSTRIDE 72

typedef __bf16 bf16;
typedef __attribute__((ext_vector_type(2))) __bf16 bf16x2;
typedef __attribute__((ext_vector_type(4))) __bf16 bf16x4;
typedef __attribute__((ext_vector_type(8))) __bf16 bf16x8;
typedef __attribute__((ext_vector_type(4))) float f32x4;

__device__ __forceinline__ void load_lds16(const bf16* g, bf16* l) {
    __builtin_amdgcn_global_load_lds((const __attribute__((address_space(1))) void*)g,
                                     (__attribute__((address_space(3))) void*)l, 16, 0, 0);
}

// v_exp_f32: D = 2^S0 (hardware transcendental)
__device__ __forceinline__ float exp2_hw(float x) { return __builtin_amdgcn_exp2f(x); }

// ---------------------------------------------------------------------------
// Fused prep (single dispatch, tasks run concurrently):
//   blocks [0, 4096):        cvt x fp32 -> xb bf16 (8 elems/thread)
//   blocks [4096, 5120):     transpose Wq -> Wtq (64x64 tiles)
//   blocks [5120, 6144):     transpose Wo -> Wto
// ---------------------------------------------------------------------------
__global__ __launch_bounds__(256)
void prep_kernel(const float* __restrict__ x, bf16* __restrict__ xb,
                 const float* __restrict__ Wq, bf16* __restrict__ Wtq,
                 const float* __restrict__ Wo, bf16* __restrict__ Wto)
{
    __shared__ bf16 T[64 * 72];
    const int bid = blockIdx.x;
    if (bid < 4096) {
        const size_t i = ((size_t)bid * 256 + threadIdx.x) * 8;
        const float4 f0 = *(const float4*)(x + i);
        const float4 f1 = *(const float4*)(x + i + 4);
        *(bf16x8*)(xb + i) = (bf16x8){(bf16)f0.x, (bf16)f0.y, (bf16)f0.z, (bf16)f0.w,
                                      (bf16)f1.x, (bf16)f1.y, (bf16)f1.z, (bf16)f1.w};
        return;
    }
    int t = bid - 4096;
    const float* W  = (t < 1024) ? Wq : Wo;
    bf16*        Wt = (t < 1024) ? Wtq : Wto;
    t &= 1023;
    const int kb = (t >> 5) * 64, nb = (t & 31) * 64;

    const int a = threadIdx.x & 31;     // k-pair index
    const int g = threadIdx.x >> 5;     // n-slice 0..7
    {
        const float* s0 = W + (size_t)(kb + 2 * a) * DIM + nb + g * 8;
        const float4 r0a = *(const float4*)(s0);
        const float4 r0b = *(const float4*)(s0 + 4);
        const float4 r1a = *(const float4*)(s0 + DIM);
        const float4 r1b = *(const float4*)(s0 + DIM + 4);
        float v0[8] = {r0a.x, r0a.y, r0a.z, r0a.w, r0b.x, r0b.y, r0b.z, r0b.w};
        float v1[8] = {r1a.x, r1a.y, r1a.z, r1a.w, r1b.x, r1b.y, r1b.z, r1b.w};
        #pragma unroll
        for (int i = 0; i < 8; ++i)
            *(bf16x2*)&T[(g * 8 + i) * 72 + 2 * a] = (bf16x2){(bf16)v0[i], (bf16)v1[i]};
    }
    __syncthreads();

    const int r  = threadIdx.x >> 2;          // output n row 0..63
    const int k0 = (threadIdx.x & 3) * 16;    // k chunk
    bf16x8 o0 = *(const bf16x8*)&T[r * 72 + k0];
    bf16x8 o1 = *(const bf16x8*)&T[r * 72 + k0 + 8];
    *(bf16x8*)(Wt + (size_t)(nb + r) * DIM + kb + k0)     = o0;
    *(bf16x8*)(Wt + (size_t)(nb + r) * DIM + kb + k0 + 8) = o1;
}

// ---------------------------------------------------------------------------
// GEMM, 8-phase counted-vmcnt. Round-5 geometry: BM=256, BN=128 (swap) with
// XCD-column placement for L2 residency of B.
//   C[M,N] = A[M,K] @ Bt[N,K]^T, bf16 in. 512 thr = 8 waves as 4M x 2N
//   (64x64 C per wave). K in 64 slices of 32; LDS = 4-slot ring, slot =
//   A[256][32] (16KB) + B[128][32] (8KB) = 24KB -> 96 KiB total, 1 block/CU.
//   Grid 256 = full chip.
// XCD map: logical = (bid&7)*32 + bid>>3; row-panel = logical&15, col-panel
//   = logical>>4 -> each XCD owns 2 col-panels x all 16 row-panels. Resident
//   B = 1 MB << 4 MB L2; 32 concurrent blocks run the same K schedule so the
//   active K-window (~270 KB) keeps all B re-reads (15/16 of B traffic) and
//   in-XCD A re-reads in L2. L3/HBM traffic ~402 MB -> ~140/25 MB.
// Per phase (slice s): ds_read 8 x b128 (swizzled) | issue 3 global_load_lds
// for slice s+3 -> barrier -> setprio(1) 16 MFMA setprio(0) -> vmcnt(6)
// -> barrier. vmcnt ledger (per-wave FIFO): 3 slices x 3 loads in flight = 9;
// wait-for-oldest-slice => vmcnt(6). Tail: vmcnt(3), vmcnt(0), none.
// Swizzle: e ^= ((e>>6)&3)<<3 (involution; applied on gload SOURCE, LDS dest
// linear (rule #21), and on ds_read addr). Validated in rounds 3/4.
// NOTE: phase count hardcodes K=2048 (64 slices); masks hardcode this shape.
// ---------------------------------------------------------------------------
#define GEMM_PHASE(S, VM, DO_STAGE)                                            \
    {                                                                          \
        const bf16* Aq = Ls + ((S) & 3) * 12288;                               \
        const bf16* Bq = Aq + 8192;                                            \
        bf16x8 a[4], b[4];                                                     \
        _Pragma("unroll")                                                      \
        for (int i = 0; i < 4; ++i) a[i] = *(const bf16x8*)(Aq + offA[i]);     \
        _Pragma("unroll")                                                      \
        for (int j = 0; j < 4; ++j) b[j] = *(const bf16x8*)(Bq + offB[j]);     \
        if (DO_STAGE) {                                                        \
            bf16* lb = Ls + (((S) + 3) & 3) * 12288 + wave * 512;              \
            const int ko = ((S) + 3) * 32;                                     \
            load_lds16(gA0 + ko, lb);                                          \
            load_lds16(gA1 + ko, lb + 4096);                                   \
            load_lds16(gB  + ko, lb + 8192);                                   \
        }                                                                      \
        __builtin_amdgcn_s_barrier();                                          \
        __builtin_amdgcn_s_setprio(1);                                         \
        _Pragma("unroll")                                                      \
        for (int i = 0; i < 4; ++i) {                                          \
            _Pragma("unroll")                                                  \
            for (int j = 0; j < 4; ++j)                                        \
                acc[i][j] = __builtin_amdgcn_mfma_f32_16x16x32_bf16(a[i], b[j], acc[i][j], 0, 0, 0); \
        }                                                                      \
        __builtin_amdgcn_s_setprio(0);                                         \
        if ((VM) == 6)      asm volatile("s_waitcnt vmcnt(6)" ::: "memory");   \
        else if ((VM) == 3) asm volatile("s_waitcnt vmcnt(3)" ::: "memory");   \
        else if ((VM) == 0) asm volatile("s_waitcnt vmcnt(0)" ::: "memory");   \
        if ((VM) >= 0) {                                                       \
            __builtin_amdgcn_s_barrier();                                      \
            asm volatile("" ::: "memory");                                     \
        }                                                                      \
    }

template<bool OUT_F32_BIAS>
__global__ __launch_bounds__(512, 2)
void gemm_bt9(const bf16* __restrict__ A, const bf16* __restrict__ Bt,
              const float* __restrict__ bias, void* __restrict__ Cptr,
              int M, int N, int K)
{
    __shared__ bf16 Ls[4 * 12288];   // 96 KiB ring: slot = A[256][32] + B[128][32]

    const int tid  = threadIdx.x;
    const int wave = tid >> 6;        // 0..7
    const int lane = tid & 63;
    const int quad = lane >> 4;
    const int l16  = lane & 15;
    const int wave_m = wave >> 1;     // 0..3: 64-row block
    const int wave_n = wave & 1;      // 0..1: 64-col block

    // XCD-column placement (bijective: 256 blocks, 256%8==0).
    const int logical = (blockIdx.x & 7) * 32 + (blockIdx.x >> 3);
    const int rowBase = (logical & 15) * 256;   // 16 row-panels
    const int colBase = (logical >> 4) * 128;   // 16 col-panels, 2 per XCD

    // s-invariant swizzled ds_read element offsets (region-relative)
    int offA[4], offB[4];
    #pragma unroll
    for (int i = 0; i < 4; ++i) {
        int e = (wave_m * 64 + i * 16 + l16) * 32 + quad * 8;
        offA[i] = e ^ (((e >> 6) & 3) << 3);
    }
    #pragma unroll
    for (int j = 0; j < 4; ++j) {
        int e = (wave_n * 64 + j * 16 + l16) * 32 + quad * 8;
        offB[j] = e ^ (((e >> 6) & 3) << 3);
    }

    // Staging source decode: lane's linear LDS slot offset o holds logical
    // elem swz(o) (involution, row-preserving) -> per-lane global addr
    // pre-swizzled; LDS dest linear. Shared column formula for all 3 chunks.
    const int rA   = tid >> 2;                                   // 0..127
    const int colg = ((tid & 3) * 8) ^ (((tid >> 3) & 3) << 3);
    const bf16* gA0 = A  + (size_t)(rowBase + rA) * K + colg;
    const bf16* gA1 = A  + (size_t)(rowBase + 128 + rA) * K + colg;
    const bf16* gB  = Bt + (size_t)(colBase + rA) * K + colg;

    f32x4 acc[4][4] = {};

    // prologue: slices 0,1,2 in flight (9 loads/wave), wait oldest -> vmcnt(6)
    #pragma unroll
    for (int s = 0; s < 3; ++s) {
        bf16* lb = Ls + s * 12288 + wave * 512;
        load_lds16(gA0 + s * 32, lb);
        load_lds16(gA1 + s * 32, lb + 4096);
        load_lds16(gB  + s * 32, lb + 8192);
    }
    asm volatile("s_waitcnt vmcnt(6)" ::: "memory");
    __builtin_amdgcn_s_barrier();
    asm volatile("" ::: "memory");

    for (int s = 0; s < 61; ++s)
        GEMM_PHASE(s, 6, true);
    GEMM_PHASE(61, 3, false);
    GEMM_PHASE(62, 0, false);
    GEMM_PHASE(63, -1, false);

    // epilogue: C row = quad*4+r, col = l16 within each 16x16 fragment
    #pragma unroll
    for (int i = 0; i < 4; ++i) {
        #pragma unroll
        for (int j = 0; j < 4; ++j) {
            #pragma unroll
            for (int r = 0; r < 4; ++r) {
                const int row = rowBase + wave_m * 64 + i * 16 + quad * 4 + r;
                const int col = colBase + wave_n * 64 + j * 16 + l16;
                const float v = acc[i][j][r];
                if (OUT_F32_BIAS) ((float*)Cptr)[(size_t)row * N + col] = v + bias[col];
                else              ((bf16*)Cptr)[(size_t)row * N + col] = (bf16)v;
            }
        }
    }
}

// ---------------------------------------------------------------------------
// Attention — REVERTED to the round-3 version (89.2 µs measured): S^T-form,
// q-tile 128, 4 waves x 32 q-rows, 2 blocks/CU, register prefetch of next
// K/V tile, KSTRIDE-136 reg-staged K commit, XCD swizzle, T5 setprio.
// (Round-4's DMA-K/swizzle/hoist bundle regressed to 97.5 µs — reverted.)
// ---------------------------------------------------------------------------
__global__ __launch_bounds__(256, 2)
void attn_kernel(const bf16* __restrict__ q, bf16* __restrict__ y)
{
    __shared__ bf16 Ks[64 * KSTRIDE];     // 17408 B  [kv][hd]
    __shared__ bf16 Vt[HDIM * VSTRIDE];   // 18432 B  [hd][kv]
    __shared__ bf16 Ps[128 * PSTRIDE];    // 18432 B  [q][kv]

    const int tid  = threadIdx.x;
    const int wave = tid >> 6;     // 0..3
    const int lane = tid & 63;
    const int quad = lane >> 4;
    const int l16  = lane & 15;

    // XCD swizzle: p -> (qt, h, b) with all qt of a (b,h) on one XCD.
    const int p   = blockIdx.x;
    const int xcd = p & 7;
    const int pos = p >> 3;
    const int g   = xcd * 4 + (pos & 3);   // (b,h) group 0..31
    const int qt  = pos >> 2;              // 0..15
    const int h   = g & 15;
    const int bb  = g >> 4;

    const bf16* qb = q + (size_t)bb * SEQ * DIM + (size_t)h * HDIM;

    // Q fragments -> registers (wave owns q rows [wave*32, wave*32+32)).
    const float qs = 0.12752820031096662f;   // (1/sqrt(128)) * log2(e)
    bf16x8 aq[2][4];
    #pragma unroll
    for (int nt = 0; nt < 2; ++nt) {
        #pragma unroll
        for (int ks = 0; ks < 4; ++ks) {
            const bf16* src = qb + (size_t)(qt * 128 + wave * 32 + nt * 16 + l16) * DIM + ks * 32 + quad * 8;
            bf16x8 v = *(const bf16x8*)src;
            bf16x8 o;
            #pragma unroll
            for (int e = 0; e < 8; ++e) o[e] = (bf16)((float)v[e] * qs);
            aq[nt][ks] = o;
        }
    }

    float lpart[2] = {0.f, 0.f};
    f32x4 yacc[2][8] = {};

    // staging index maps (both conflict-free, round-6 audit)
    const int kr   = tid >> 2;         // kv row 0..63 (Ks path)
    const int koff = (tid & 3) * 32;
    const int sp   = tid & 31;         // kv pair (Vt path)
    const int ss   = tid >> 5;         // hd slice of 16

    const bf16* srcK = qb + (size_t)kr * DIM + koff;
    const bf16* srcV = qb + (size_t)(2 * sp) * DIM + ss * 16;

    // prologue: prefetch tile 0 into registers
    bf16x8 kreg[4], va[2], vb[2];
    #pragma unroll
    for (int c = 0; c < 4; ++c) kreg[c] = *(const bf16x8*)(srcK + c * 8);
    va[0] = *(const bf16x8*)(srcV + 0);
    va[1] = *(const bf16x8*)(srcV + 8);
    vb[0] = *(const bf16x8*)(srcV + DIM + 0);
    vb[1] = *(const bf16x8*)(srcV + DIM + 8);

    for (int kt = 0; kt < SEQ / 64; ++kt) {
        __syncthreads();   // prev iteration done reading Ks/Vt

        // commit prefetched tile to LDS
        #pragma unroll
        for (int c = 0; c < 4; ++c)
            *(bf16x8*)&Ks[kr * KSTRIDE + koff + c * 8] = kreg[c];
        #pragma unroll
        for (int c = 0; c < 2; ++c)
            #pragma unroll
            for (int e = 0; e < 8; ++e)
                *(bf16x2*)&Vt[(ss * 16 + c * 8 + e) * VSTRIDE + 2 * sp] = (bf16x2){va[c][e], vb[c][e]};

        // prefetch NEXT tile (overlaps the compute phase below)
        if (kt + 1 < SEQ / 64) {
            const bf16* nK = srcK + (size_t)(kt + 1) * 64 * DIM;
            const bf16* nV = srcV + (size_t)(kt + 1) * 64 * DIM;
            #pragma unroll
            for (int c = 0; c < 4; ++c) kreg[c] = *(const bf16x8*)(nK + c * 8);
            va[0] = *(const bf16x8*)(nV + 0);
            va[1] = *(const bf16x8*)(nV + 8);
            vb[0] = *(const bf16x8*)(nV + DIM + 0);
            vb[1] = *(const bf16x8*)(nV + DIM + 8);
        }
        __syncthreads();

        // S^T phase per 16-kv strip (mt): MFMA(A=Ks-frag, B=aq).
        // C-layout of S^T: kv = mt*16 + quad*4 + r, q = wave*32 + nt*16 + l16.
        #pragma unroll
        for (int mt = 0; mt < 4; ++mt) {
            bf16x8 ak[4];
            #pragma unroll
            for (int ks = 0; ks < 4; ++ks)
                ak[ks] = *(const bf16x8*)&Ks[(mt * 16 + l16) * KSTRIDE + ks * 32 + quad * 8];
            f32x4 s[2] = {};
            __builtin_amdgcn_s_setprio(1);
            #pragma unroll
            for (int ks = 0; ks < 4; ++ks)
                #pragma unroll
                for (int nt = 0; nt < 2; ++nt)
                    s[nt] = __builtin_amdgcn_mfma_f32_16x16x32_bf16(ak[ks], aq[nt][ks], s[nt], 0, 0, 0);
            __builtin_amdgcn_s_setprio(0);
            #pragma unroll
            for (int nt = 0; nt < 2; ++nt) {
                float p0 = exp2_hw(s[nt][0]);
                float p1 = exp2_hw(s[nt][1]);
                float p2 = exp2_hw(s[nt][2]);
                float p3 = exp2_hw(s[nt][3]);
                lpart[nt] += (p0 + p1) + (p2 + p3);
                *(bf16x4*)&Ps[(wave * 32 + nt * 16 + l16) * PSTRIDE + mt * 16 + quad * 4] =
                    (bf16x4){(bf16)p0, (bf16)p1, (bf16)p2, (bf16)p3};
            }
        }

        // PV: Y += P @ V. A = own-wave P rows (in-wave LDS dep only), B = V^T.
        #pragma unroll
        for (int ks2 = 0; ks2 < 2; ++ks2) {
            bf16x8 ap[2];
            #pragma unroll
            for (int i = 0; i < 2; ++i)
                ap[i] = *(const bf16x8*)&Ps[(wave * 32 + i * 16 + l16) * PSTRIDE + ks2 * 32 + quad * 8];
            __builtin_amdgcn_s_setprio(1);
            #pragma unroll
            for (int n = 0; n < 8; ++n) {
                bf16x8 bv = *(const bf16x8*)&Vt[(n * 16 + l16) * VSTRIDE + ks2 * 32 + quad * 8];
                #pragma unroll
                for (int i = 0; i < 2; ++i)
                    yacc[i][n] = __builtin_amdgcn_mfma_f32_16x16x32_bf16(ap[i], bv, yacc[i][n], 0, 0, 0);
            }
            __builtin_amdgcn_s_setprio(0);
        }
    }

    // denominators: reduce across the 4 quad-lanes sharing each q.
    float lfull[2];
    #pragma unroll
    for (int nt = 0; nt < 2; ++nt) {
        float l = lpart[nt];
        l += __shfl_xor(l, 16);
        l += __shfl_xor(l, 32);
        lfull[nt] = l;
    }

    // epilogue: yacc C-layout row = wave*32 + i*16 + quad*4 + r (q),
    // col = n*16 + l16 (hd).
    bf16* yb = y + (size_t)bb * SEQ * DIM + (size_t)(qt * 128) * DIM + (size_t)h * HDIM;
    #pragma unroll
    for (int i = 0; i < 2; ++i) {
        #pragma unroll
        for (int r = 0; r < 4; ++r) {
            const float lv  = __shfl(lfull[i], (lane & 48) | (quad * 4 + r));
            const float inv = 1.f / lv;
            const int row = wave * 32 + i * 16 + quad * 4 + r;
            #pragma unroll
            for (int n = 0; n < 8; ++n)
                yb[(size_t)row * DIM + n * 16 + l16] = (bf16)(yacc[i][n][r] * inv);
        }
    }
}

// ---------------------------------------------------------------------------
// Workspace layout (unchanged):
//   ws[0 .. N)        qws  (gemm1 out, attn in)           N = 16.78 MB
//   ws[N .. 2N)       yws  (attn out, gemm2 in); first 8.39 MB doubles as Wtq
//   ws[2N .. 2N+W)    Wto                                  W = 8.39 MB
//   d_out[0 .. N)     xb   (bf16 scratch; dead before gemm2 overwrites d_out)
// ---------------------------------------------------------------------------
extern "C" void kernel_launch(void* const* d_in, const int* in_sizes, int n_in,
                              void* d_out, int out_size, void* d_ws, size_t ws_size,
                              hipStream_t stream)
{
    const float* x  = (const float*)d_in[0];
    const float* Wq = (const float*)d_in[1];
    const float* Wo = (const float*)d_in[2];
    const float* bo = (const float*)d_in[3];
    float* out = (float*)d_out;

    const size_t NELEM = (size_t)BATCH * SEQ * DIM;
    bf16* qws = (bf16*)d_ws;
    bf16* yws = qws + NELEM;
    bf16* Wtq = yws;                 // aliased: safe, gemm1 precedes attn
    bf16* Wto = qws + 2 * NELEM;
    bf16* xb  = (bf16*)d_out;        // scratch inside d_out, dead by gemm2

    const int M = BATCH * SEQ;       // 4096

    prep_kernel<<<6144, 256, 0, stream>>>(x, xb, Wq, Wtq, Wo, Wto);
    gemm_bt9<false><<<256, 512, 0, stream>>>(xb, Wtq, nullptr, qws, M, DIM, DIM);
    attn_kernel<<<512, 256, 0, stream>>>(qws, yws);
    gemm_bt9<true><<<256, 512, 0, stream>>>(yws, Wto, bo, out, M, DIM, DIM);
}

// Round 8
// 262.571 us; speedup vs baseline: 1.0433x; 1.0129x over previous
//
#include <hip/hip_runtime.h>
#include <hip/hip_bf16.h>

#define BATCH 2
#define SEQ   2048
#define DIM   2048
#define NHEAD 16
#define HDIM  128

// LDS strides (elements) for attn V/P tiles. Multiples of 8 (16B alignment).
// Ks is linear [64][128] with a row-XOR swizzle (see attn_kernel).
#define VSTRIDE 72
#define PSTRIDE 72

typedef __bf16 bf16;
typedef __attribute__((ext_vector_type(2))) __bf16 bf16x2;
typedef __attribute__((ext_vector_type(4))) __bf16 bf16x4;
typedef __attribute__((ext_vector_type(8))) __bf16 bf16x8;
typedef __attribute__((ext_vector_type(4))) float f32x4;

__device__ __forceinline__ void load_lds16(const bf16* g, bf16* l) {
    __builtin_amdgcn_global_load_lds((const __attribute__((address_space(1))) void*)g,
                                     (__attribute__((address_space(3))) void*)l, 16, 0, 0);
}

// v_exp_f32: D = 2^S0 (hardware transcendental)
__device__ __forceinline__ float exp2_hw(float x) { return __builtin_amdgcn_exp2f(x); }

// ---------------------------------------------------------------------------
// Fused prep (single dispatch, tasks run concurrently):
//   blocks [0, 4096):        cvt x fp32 -> xb bf16 (8 elems/thread)
//   blocks [4096, 5120):     transpose Wq -> Wtq (64x64 tiles)
//   blocks [5120, 6144):     transpose Wo -> Wto
// ---------------------------------------------------------------------------
__global__ __launch_bounds__(256)
void prep_kernel(const float* __restrict__ x, bf16* __restrict__ xb,
                 const float* __restrict__ Wq, bf16* __restrict__ Wtq,
                 const float* __restrict__ Wo, bf16* __restrict__ Wto)
{
    __shared__ bf16 T[64 * 72];
    const int bid = blockIdx.x;
    if (bid < 4096) {
        const size_t i = ((size_t)bid * 256 + threadIdx.x) * 8;
        const float4 f0 = *(const float4*)(x + i);
        const float4 f1 = *(const float4*)(x + i + 4);
        *(bf16x8*)(xb + i) = (bf16x8){(bf16)f0.x, (bf16)f0.y, (bf16)f0.z, (bf16)f0.w,
                                      (bf16)f1.x, (bf16)f1.y, (bf16)f1.z, (bf16)f1.w};
        return;
    }
    int t = bid - 4096;
    const float* W  = (t < 1024) ? Wq : Wo;
    bf16*        Wt = (t < 1024) ? Wtq : Wto;
    t &= 1023;
    const int kb = (t >> 5) * 64, nb = (t & 31) * 64;

    const int a = threadIdx.x & 31;     // k-pair index
    const int g = threadIdx.x >> 5;     // n-slice 0..7
    {
        const float* s0 = W + (size_t)(kb + 2 * a) * DIM + nb + g * 8;
        const float4 r0a = *(const float4*)(s0);
        const float4 r0b = *(const float4*)(s0 + 4);
        const float4 r1a = *(const float4*)(s0 + DIM);
        const float4 r1b = *(const float4*)(s0 + DIM + 4);
        float v0[8] = {r0a.x, r0a.y, r0a.z, r0a.w, r0b.x, r0b.y, r0b.z, r0b.w};
        float v1[8] = {r1a.x, r1a.y, r1a.z, r1a.w, r1b.x, r1b.y, r1b.z, r1b.w};
        #pragma unroll
        for (int i = 0; i < 8; ++i)
            *(bf16x2*)&T[(g * 8 + i) * 72 + 2 * a] = (bf16x2){(bf16)v0[i], (bf16)v1[i]};
    }
    __syncthreads();

    const int r  = threadIdx.x >> 2;          // output n row 0..63
    const int k0 = (threadIdx.x & 3) * 16;    // k chunk
    bf16x8 o0 = *(const bf16x8*)&T[r * 72 + k0];
    bf16x8 o1 = *(const bf16x8*)&T[r * 72 + k0 + 8];
    *(bf16x8*)(Wt + (size_t)(nb + r) * DIM + kb + k0)     = o0;
    *(bf16x8*)(Wt + (size_t)(nb + r) * DIM + kb + k0 + 8) = o1;
}

// ---------------------------------------------------------------------------
// GEMM, 8-phase counted-vmcnt (round-3 code verbatim — best measured):
//   C[M,N] = A[M,K] @ Bt[N,K]^T, bf16 in. BM=128, BN=256, 8 waves 2Mx4N,
//   K in 64 slices of 32, 4-slot LDS ring (96 KiB), 256 blocks = 256 CUs.
// ---------------------------------------------------------------------------
#define GEMM_PHASE(S, VM, DO_STAGE)                                            \
    {                                                                          \
        const bf16* Aq = Ls + ((S) & 3) * 12288;                               \
        const bf16* Bq = Aq + 4096;                                            \
        bf16x8 a[4], b[4];                                                     \
        _Pragma("unroll")                                                      \
        for (int i = 0; i < 4; ++i) a[i] = *(const bf16x8*)(Aq + offA[i]);     \
        _Pragma("unroll")                                                      \
        for (int j = 0; j < 4; ++j) b[j] = *(const bf16x8*)(Bq + offB[j]);     \
        if (DO_STAGE) {                                                        \
            bf16* lb = Ls + (((S) + 3) & 3) * 12288 + wave * 512;              \
            const int ko = ((S) + 3) * 32;                                     \
            load_lds16(gA + ko, lb);                                           \
            load_lds16(gB0 + ko, lb + 4096);                                   \
            load_lds16(gB1 + ko, lb + 8192);                                   \
        }                                                                      \
        __builtin_amdgcn_s_barrier();                                          \
        __builtin_amdgcn_s_setprio(1);                                         \
        _Pragma("unroll")                                                      \
        for (int i = 0; i < 4; ++i) {                                          \
            _Pragma("unroll")                                                  \
            for (int j = 0; j < 4; ++j)                                        \
                acc[i][j] = __builtin_amdgcn_mfma_f32_16x16x32_bf16(a[i], b[j], acc[i][j], 0, 0, 0); \
        }                                                                      \
        __builtin_amdgcn_s_setprio(0);                                         \
        if ((VM) == 6)      asm volatile("s_waitcnt vmcnt(6)" ::: "memory");   \
        else if ((VM) == 3) asm volatile("s_waitcnt vmcnt(3)" ::: "memory");   \
        else if ((VM) == 0) asm volatile("s_waitcnt vmcnt(0)" ::: "memory");   \
        if ((VM) >= 0) {                                                       \
            __builtin_amdgcn_s_barrier();                                      \
            asm volatile("" ::: "memory");                                     \
        }                                                                      \
    }

template<bool OUT_F32_BIAS>
__global__ __launch_bounds__(512, 2)
void gemm_bt8(const bf16* __restrict__ A, const bf16* __restrict__ Bt,
              const float* __restrict__ bias, void* __restrict__ Cptr,
              int M, int N, int K)
{
    __shared__ bf16 Ls[4 * 12288];   // 96 KiB ring: slot = A[128][32] + B[256][32]

    const int tid  = threadIdx.x;
    const int wave = tid >> 6;        // 0..7
    const int lane = tid & 63;
    const int quad = lane >> 4;
    const int l16  = lane & 15;
    const int wr   = wave >> 2;       // 0..1: 64-row block
    const int wc   = wave & 3;        // 0..3: 64-col block

    // XCD swizzle (bijective: 256 blocks, 256%8==0).
    const int cpx = gridDim.x >> 3;
    const int logical = (blockIdx.x & 7) * cpx + (blockIdx.x >> 3);
    const int rowBase = (logical >> 3) * 128;   // NT = N/256 = 8
    const int colBase = (logical & 7) * 256;

    // s-invariant swizzled ds_read element offsets (region-relative)
    int offA[4], offB[4];
    #pragma unroll
    for (int i = 0; i < 4; ++i) {
        int e = (wr * 64 + i * 16 + l16) * 32 + quad * 8;
        offA[i] = e ^ (((e >> 6) & 3) << 3);
    }
    #pragma unroll
    for (int j = 0; j < 4; ++j) {
        int e = (wc * 64 + j * 16 + l16) * 32 + quad * 8;
        offB[j] = e ^ (((e >> 6) & 3) << 3);
    }

    // Staging source decode: lane's linear LDS slot o holds logical elem
    // swz(o) (involution) -> per-lane global addr pre-swizzled; LDS linear.
    const int oA  = wave * 512 + lane * 8;
    const int eA  = oA ^ (((oA >> 6) & 3) << 3);
    const bf16* gA  = A  + (size_t)(rowBase + (eA >> 5)) * K + (eA & 31);
    const int oB0 = wave * 512 + lane * 8;
    const int eB0 = oB0 ^ (((oB0 >> 6) & 3) << 3);
    const bf16* gB0 = Bt + (size_t)(colBase + (eB0 >> 5)) * K + (eB0 & 31);
    const int oB1 = 4096 + wave * 512 + lane * 8;
    const int eB1 = oB1 ^ (((oB1 >> 6) & 3) << 3);
    const bf16* gB1 = Bt + (size_t)(colBase + ((eB1 - 4096) >> 5) + 128) * K + (eB1 & 31);

    f32x4 acc[4][4] = {};

    // prologue: slices 0,1,2 in flight (9 loads/wave), wait oldest -> vmcnt(6)
    #pragma unroll
    for (int s = 0; s < 3; ++s) {
        bf16* lb = Ls + s * 12288 + wave * 512;
        load_lds16(gA  + s * 32, lb);
        load_lds16(gB0 + s * 32, lb + 4096);
        load_lds16(gB1 + s * 32, lb + 8192);
    }
    asm volatile("s_waitcnt vmcnt(6)" ::: "memory");
    __builtin_amdgcn_s_barrier();
    asm volatile("" ::: "memory");

    for (int s = 0; s < 61; ++s)
        GEMM_PHASE(s, 6, true);
    GEMM_PHASE(61, 3, false);
    GEMM_PHASE(62, 0, false);
    GEMM_PHASE(63, -1, false);

    // epilogue: C row = quad*4+r, col = l16 within each 16x16 fragment
    #pragma unroll
    for (int i = 0; i < 4; ++i) {
        #pragma unroll
        for (int j = 0; j < 4; ++j) {
            #pragma unroll
            for (int r = 0; r < 4; ++r) {
                const int row = rowBase + wr * 64 + i * 16 + quad * 4 + r;
                const int col = colBase + wc * 64 + j * 16 + l16;
                const float v = acc[i][j][r];
                if (OUT_F32_BIAS) ((float*)Cptr)[(size_t)row * N + col] = v + bias[col];
                else              ((bf16*)Cptr)[(size_t)row * N + col] = (bf16)v;
            }
        }
    }
}

// ---------------------------------------------------------------------------
// Attention, round-6 change (second resubmission — two infra failures, the
// change has never executed): Ks linear [64][128] with row-XOR swizzle:
//   elem-col' = col ^ ((row & 7) << 3)
// applied on BOTH the reg-staged commit and the ak ds_read (pure column
// relabeling per row -> bit-identical math). XOR touches elem bits 3-4 only
// -> bf16x8 contiguity + 16B alignment preserved. V/P paths, phase order,
// setprio, epilogue unchanged from the round-3 kernel (89-91 us measured).
// Pre-committed read: conflicts>=2x down + dur down => confirmed; conflicts
// down + dur flat => latency-bound, pivot to barrier restructure; conflicts
// flat => Ks was never the source, audit V-commit next.
// ---------------------------------------------------------------------------
__global__ __launch_bounds__(256, 2)
void attn_kernel(const bf16* __restrict__ q, bf16* __restrict__ y)
{
    __shared__ bf16 Ks[64 * 128];         // 16384 B  [kv][hd] linear+XOR
    __shared__ bf16 Vt[HDIM * VSTRIDE];   // 18432 B  [hd][kv]
    __shared__ bf16 Ps[128 * PSTRIDE];    // 18432 B  [q][kv]

    const int tid  = threadIdx.x;
    const int wave = tid >> 6;     // 0..3
    const int lane = tid & 63;
    const int quad = lane >> 4;
    const int l16  = lane & 15;

    // XCD swizzle: p -> (qt, h, b) with all qt of a (b,h) on one XCD.
    const int p   = blockIdx.x;
    const int xcd = p & 7;
    const int pos = p >> 3;
    const int g   = xcd * 4 + (pos & 3);   // (b,h) group 0..31
    const int qt  = pos >> 2;              // 0..15
    const int h   = g & 15;
    const int bb  = g >> 4;

    const bf16* qb = q + (size_t)bb * SEQ * DIM + (size_t)h * HDIM;

    // Q fragments -> registers (wave owns q rows [wave*32, wave*32+32)).
    const float qs = 0.12752820031096662f;   // (1/sqrt(128)) * log2(e)
    bf16x8 aq[2][4];
    #pragma unroll
    for (int nt = 0; nt < 2; ++nt) {
        #pragma unroll
        for (int ks = 0; ks < 4; ++ks) {
            const bf16* src = qb + (size_t)(qt * 128 + wave * 32 + nt * 16 + l16) * DIM + ks * 32 + quad * 8;
            bf16x8 v = *(const bf16x8*)src;
            bf16x8 o;
            #pragma unroll
            for (int e = 0; e < 8; ++e) o[e] = (bf16)((float)v[e] * qs);
            aq[nt][ks] = o;
        }
    }

    float lpart[2] = {0.f, 0.f};
    f32x4 yacc[2][8] = {};

    // staging index maps
    const int kr   = tid >> 2;         // kv row 0..63 (Ks path)
    const int koff = (tid & 3) * 32;
    const int sp   = tid & 31;         // kv pair (Vt path)
    const int ss   = tid >> 5;         // hd slice of 16

    const bf16* srcK = qb + (size_t)kr * DIM + koff;
    const bf16* srcV = qb + (size_t)(2 * sp) * DIM + ss * 16;

    // prologue: prefetch tile 0 into registers
    bf16x8 kreg[4], va[2], vb[2];
    #pragma unroll
    for (int c = 0; c < 4; ++c) kreg[c] = *(const bf16x8*)(srcK + c * 8);
    va[0] = *(const bf16x8*)(srcV + 0);
    va[1] = *(const bf16x8*)(srcV + 8);
    vb[0] = *(const bf16x8*)(srcV + DIM + 0);
    vb[1] = *(const bf16x8*)(srcV + DIM + 8);

    for (int kt = 0; kt < SEQ / 64; ++kt) {
        __syncthreads();   // prev iteration done reading Ks/Vt

        // commit prefetched tile to LDS (Ks: XOR-swizzled column)
        #pragma unroll
        for (int c = 0; c < 4; ++c)
            *(bf16x8*)&Ks[kr * 128 + ((koff + c * 8) ^ ((kr & 7) << 3))] = kreg[c];
        #pragma unroll
        for (int c = 0; c < 2; ++c)
            #pragma unroll
            for (int e = 0; e < 8; ++e)
                *(bf16x2*)&Vt[(ss * 16 + c * 8 + e) * VSTRIDE + 2 * sp] = (bf16x2){va[c][e], vb[c][e]};

        // prefetch NEXT tile (overlaps the compute phase below)
        if (kt + 1 < SEQ / 64) {
            const bf16* nK = srcK + (size_t)(kt + 1) * 64 * DIM;
            const bf16* nV = srcV + (size_t)(kt + 1) * 64 * DIM;
            #pragma unroll
            for (int c = 0; c < 4; ++c) kreg[c] = *(const bf16x8*)(nK + c * 8);
            va[0] = *(const bf16x8*)(nV + 0);
            va[1] = *(const bf16x8*)(nV + 8);
            vb[0] = *(const bf16x8*)(nV + DIM + 0);
            vb[1] = *(const bf16x8*)(nV + DIM + 8);
        }
        __syncthreads();

        // S^T phase per 16-kv strip (mt): MFMA(A=Ks-frag, B=aq).
        // C-layout of S^T: kv = mt*16 + quad*4 + r, q = wave*32 + nt*16 + l16.
        #pragma unroll
        for (int mt = 0; mt < 4; ++mt) {
            bf16x8 ak[4];
            #pragma unroll
            for (int ks = 0; ks < 4; ++ks)
                ak[ks] = *(const bf16x8*)&Ks[(mt * 16 + l16) * 128 + ((ks * 32 + quad * 8) ^ ((l16 & 7) << 3))];
            f32x4 s[2] = {};
            __builtin_amdgcn_s_setprio(1);
            #pragma unroll
            for (int ks = 0; ks < 4; ++ks)
                #pragma unroll
                for (int nt = 0; nt < 2; ++nt)
                    s[nt] = __builtin_amdgcn_mfma_f32_16x16x32_bf16(ak[ks], aq[nt][ks], s[nt], 0, 0, 0);
            __builtin_amdgcn_s_setprio(0);
            #pragma unroll
            for (int nt = 0; nt < 2; ++nt) {
                float p0 = exp2_hw(s[nt][0]);
                float p1 = exp2_hw(s[nt][1]);
                float p2 = exp2_hw(s[nt][2]);
                float p3 = exp2_hw(s[nt][3]);
                lpart[nt] += (p0 + p1) + (p2 + p3);
                *(bf16x4*)&Ps[(wave * 32 + nt * 16 + l16) * PSTRIDE + mt * 16 + quad * 4] =
                    (bf16x4){(bf16)p0, (bf16)p1, (bf16)p2, (bf16)p3};
            }
        }

        // PV: Y += P @ V. A = own-wave P rows (in-wave LDS dep only), B = V^T.
        #pragma unroll
        for (int ks2 = 0; ks2 < 2; ++ks2) {
            bf16x8 ap[2];
            #pragma unroll
            for (int i = 0; i < 2; ++i)
                ap[i] = *(const bf16x8*)&Ps[(wave * 32 + i * 16 + l16) * PSTRIDE + ks2 * 32 + quad * 8];
            __builtin_amdgcn_s_setprio(1);
            #pragma unroll
            for (int n = 0; n < 8; ++n) {
                bf16x8 bv = *(const bf16x8*)&Vt[(n * 16 + l16) * VSTRIDE + ks2 * 32 + quad * 8];
                #pragma unroll
                for (int i = 0; i < 2; ++i)
                    yacc[i][n] = __builtin_amdgcn_mfma_f32_16x16x32_bf16(ap[i], bv, yacc[i][n], 0, 0, 0);
            }
            __builtin_amdgcn_s_setprio(0);
        }
    }

    // denominators: reduce across the 4 quad-lanes sharing each q.
    float lfull[2];
    #pragma unroll
    for (int nt = 0; nt < 2; ++nt) {
        float l = lpart[nt];
        l += __shfl_xor(l, 16);
        l += __shfl_xor(l, 32);
        lfull[nt] = l;
    }

    // epilogue: yacc C-layout row = wave*32 + i*16 + quad*4 + r (q),
    // col = n*16 + l16 (hd).
    bf16* yb = y + (size_t)bb * SEQ * DIM + (size_t)(qt * 128) * DIM + (size_t)h * HDIM;
    #pragma unroll
    for (int i = 0; i < 2; ++i) {
        #pragma unroll
        for (int r = 0; r < 4; ++r) {
            const float lv  = __shfl(lfull[i], (lane & 48) | (quad * 4 + r));
            const float inv = 1.f / lv;
            const int row = wave * 32 + i * 16 + quad * 4 + r;
            #pragma unroll
            for (int n = 0; n < 8; ++n)
                yb[(size_t)row * DIM + n * 16 + l16] = (bf16)(yacc[i][n][r] * inv);
        }
    }
}

// ---------------------------------------------------------------------------
// Workspace layout (unchanged):
//   ws[0 .. N)        qws  (gemm1 out, attn in)           N = 16.78 MB
//   ws[N .. 2N)       yws  (attn out, gemm2 in); first 8.39 MB doubles as Wtq
//   ws[2N .. 2N+W)    Wto                                  W = 8.39 MB
//   d_out[0 .. N)     xb   (bf16 scratch; dead before gemm2 overwrites d_out)
// ---------------------------------------------------------------------------
extern "C" void kernel_launch(void* const* d_in, const int* in_sizes, int n_in,
                              void* d_out, int out_size, void* d_ws, size_t ws_size,
                              hipStream_t stream)
{
    const float* x  = (const float*)d_in[0];
    const float* Wq = (const float*)d_in[1];
    const float* Wo = (const float*)d_in[2];
    const float* bo = (const float*)d_in[3];
    float* out = (float*)d_out;

    const size_t NELEM = (size_t)BATCH * SEQ * DIM;
    bf16* qws = (bf16*)d_ws;
    bf16* yws = qws + NELEM;
    bf16* Wtq = yws;                 // aliased: safe, gemm1 precedes attn
    bf16* Wto = qws + 2 * NELEM;
    bf16* xb  = (bf16*)d_out;        // scratch inside d_out, dead by gemm2

    const int M = BATCH * SEQ;       // 4096

    prep_kernel<<<6144, 256, 0, stream>>>(x, xb, Wq, Wtq, Wo, Wto);
    gemm_bt8<false><<<256, 512, 0, stream>>>(xb, Wtq, nullptr, qws, M, DIM, DIM);
    attn_kernel<<<512, 256, 0, stream>>>(qws, yws);
    gemm_bt8<true><<<256, 512, 0, stream>>>(yws, Wto, bo, out, M, DIM, DIM);
}